// Round 22
// baseline (86.003 us; speedup 1.0000x reference)
//
#include <hip/hip_runtime.h>
#include <math.h>

#define B_TOTAL 8192
#define C_DIM 62
#define CC (C_DIM * C_DIM)   // 3844 floats
#define EPSV 1e-4f
#define NSWEEP 4
#define WSTRIDE 72
#define YSTR 9

// NOTE (R15): block = 1 wave; __syncthreads = vital scheduling fence (keeps
// VGPR bounded). NOTE (R16): eig1 removed — rec(M1)=M1 for this data.
// NOTE (R17): Y-loop w1 reads via wave-uniform global (scalar s_load path).
// NOTE (R22): X is SYMMETRIC — read only the lower triangle (bytes halve;
// A is L3-BW-bound per R19 probe). M1 = G + G^T with G = w1^T H w1,
// H = strict-lower + 0.5*diag. B reconstructs via a[j] = G[e][j] + G[j][e].
// B phase = R18 verbatim (R21's ILP-2 pairing regressed; 0-for-6 on B).

// ---------- cross-lane xor-shuffle: DPP (VALU) for masks 1..3, swizzle 4..7 ----------
template<int M> __device__ __forceinline__ float sx(float x) {
  int xi = __builtin_bit_cast(int, x);
  int r;
  if constexpr (M == 1)      r = __builtin_amdgcn_update_dpp(xi, xi, 0xB1, 0xF, 0xF, false);
  else if constexpr (M == 2) r = __builtin_amdgcn_update_dpp(xi, xi, 0x4E, 0xF, 0xF, false);
  else if constexpr (M == 3) r = __builtin_amdgcn_update_dpp(xi, xi, 0x1B, 0xF, 0xF, false);
  else                       r = __builtin_amdgcn_ds_swizzle(xi, (M << 10) | 0x1F);
  return __builtin_bit_cast(float, r);
}

// in-register xor-permute: r[j] <- r[j ^ e]
__device__ __forceinline__ void xperm8(float r[8], const int e) {
  const bool b0 = (e & 1) != 0, b1 = (e & 2) != 0, b2 = (e & 4) != 0;
  float t0[8], t1[8];
#pragma unroll
  for (int j = 0; j < 8; ++j) t0[j] = b0 ? r[j ^ 1] : r[j];
#pragma unroll
  for (int j = 0; j < 8; ++j) t1[j] = b1 ? t0[j ^ 2] : t0[j];
#pragma unroll
  for (int j = 0; j < 8; ++j) r[j] = b2 ? t1[j ^ 4] : t1[j];
}

// ---------- one tournament stage, XOR-relative storage ----------
template<int M>
__device__ __forceinline__ void jstage(float ar[8], float pr[8], const int e) {
  constexpr int HB = (M >= 4) ? 4 : ((M >= 2) ? 2 : 1);
  constexpr int A1 = (M == 1) ? 2 : 1;
  constexpr int A2 = (M <= 3) ? 4 : 2;
  const bool low = (e & HB) == 0;
  float d_oth = sx<M>(ar[0]);
  float o_oth = sx<M>(ar[M]);
  float apq = 0.5f * (ar[M] + o_oth);
  float app = low ? ar[0] : d_oth;
  float aqq = low ? d_oth : ar[0];
  float taun = aqq - app;
  float den = fabsf(taun) + sqrtf(fmaf(taun, taun, 4.f * apq * apq)) + 1e-38f;
  float t = (2.f * apq) * copysignf(1.f, taun) * __builtin_amdgcn_rcpf(den);
  float c = rsqrtf(fmaf(t, t, 1.f));
  float s = t * c;
  float cg[8], sg[8];
  cg[0] = c;  sg[0] = s;
  cg[A1] = sx<A1>(c);  sg[A1] = sx<A1>(s);
  cg[A2] = sx<A2>(c);  sg[A2] = sx<A2>(s);
  cg[A1 ^ A2] = sx<A2>(cg[A1]);  sg[A1 ^ A2] = sx<A2>(sg[A1]);
  float an[8], pn[8];
#pragma unroll
  for (int d = 0; d < 8; ++d) {
    const int rep = (d == 0 || d == A1 || d == A2 || d == (A1 ^ A2)) ? d : (d ^ M);
    const bool flip = (d & HB) != 0;
    float sD = sg[rep];
    float ss = (low != flip) ? -sD : sD;
    an[d] = fmaf(cg[rep], ar[d], ss * ar[d ^ M]);
    pn[d] = fmaf(cg[rep], pr[d], ss * pr[d ^ M]);
  }
#pragma unroll
  for (int d = 0; d < 8; ++d) pr[d] = pn[d];
  float scol = low ? -s : s;
  float aoth[8];
#pragma unroll
  for (int d = 0; d < 8; ++d) aoth[d] = sx<M>(an[d ^ M]);
#pragma unroll
  for (int d = 0; d < 8; ++d) ar[d] = fmaf(c, an[d], scol * aoth[d]);
}

__device__ __forceinline__ void jacobi8rel(float ar[8], float u[8], const int e) {
  float pr[8];
#pragma unroll
  for (int i = 0; i < 8; ++i) pr[i] = (i == 0) ? 1.f : 0.f;
#pragma unroll 1
  for (int sweep = 0; sweep < NSWEEP; ++sweep) {
    jstage<1>(ar, pr, e);
    jstage<2>(ar, pr, e);
    jstage<3>(ar, pr, e);
    jstage<4>(ar, pr, e);
    jstage<5>(ar, pr, e);
    jstage<6>(ar, pr, e);
    jstage<7>(ar, pr, e);
  }
  u[0] = pr[0];
  u[1] = sx<1>(pr[1]);
  u[2] = sx<2>(pr[2]);
  u[3] = sx<3>(pr[3]);
  u[4] = sx<4>(pr[4]);
  u[5] = sx<5>(pr[5]);
  u[6] = sx<6>(pr[6]);
  u[7] = sx<7>(pr[7]);
  xperm8(u, e);
}

// ---------------- fused kernel: 1 wave = 8 batches ----------------
__global__ __launch_bounds__(64) void spdnet_kernel(
    const float* __restrict__ X, const float* __restrict__ w1,
    const float* __restrict__ w2, const float* __restrict__ fc,
    float* __restrict__ out) {
  __shared__ __align__(16) float w1s[C_DIM * 8];
  __shared__ float Ys[C_DIM * YSTR];
  __shared__ float M1s[8 * 64];                  // holds G (M1 = G + G^T)
  __shared__ __align__(16) float Wbuf[8 * WSTRIDE];
  __shared__ float lwbuf[64];
  __shared__ float w2s[64];
  __shared__ float fcs[128];
  const int lane = threadIdx.x;
  const int b0 = blockIdx.x * 8;

  w2s[lane] = w2[lane];
  fcs[lane] = fc[lane];
  fcs[lane + 64] = fc[lane + 64];
  if (lane < C_DIM) {
    *(float4*)(w1s + lane * 8)     = *(const float4*)(w1 + lane * 8);
    *(float4*)(w1s + lane * 8 + 4) = *(const float4*)(w1 + lane * 8 + 4);
  }

  // triangle loader: lane c reads only X[c][0..c]; scales: d<c ->1, d==c ->0.5,
  // d>c ->0 (zero-filled). Exec-masked loads halve memory traffic.
  auto loadrow = [&](float* r, int g) {
    if (lane < C_DIM) {
      const float* row = X + (size_t)(b0 + g) * CC + lane * C_DIM;
#pragma unroll
      for (int k = 0; k < 31; ++k) {
        if (2 * k <= lane) {
          float2 t = *(const float2*)(row + 2 * k);
          float s0 = (2 * k < lane) ? 1.f : 0.5f;
          float s1 = (2 * k + 1 < lane) ? 1.f : ((2 * k + 1 == lane) ? 0.5f : 0.f);
          r[2 * k]     = t.x * s0;
          r[2 * k + 1] = t.y * s1;
        } else {
          r[2 * k] = 0.f;
          r[2 * k + 1] = 0.f;
        }
      }
    }
  };

  // ---- A phase: G[g] = w1^T H w1, ping-pong register prefetch ----
  float xrA[C_DIM], xrB[C_DIM];
  loadrow(xrA, 0);
  __syncthreads();

  auto computeA = [&](const float* xr, int g) {
    if (lane < C_DIM) {
      float a0=0.f,a1=0.f,a2=0.f,a3=0.f,a4=0.f,a5=0.f,a6=0.f,a7=0.f;
#pragma unroll
      for (int d = 0; d < C_DIM; ++d) {
        float x = xr[d];
        const float* wr = w1 + d * 8;   // wave-uniform -> scalar path
        a0 = fmaf(x, wr[0], a0); a1 = fmaf(x, wr[1], a1);
        a2 = fmaf(x, wr[2], a2); a3 = fmaf(x, wr[3], a3);
        a4 = fmaf(x, wr[4], a4); a5 = fmaf(x, wr[5], a5);
        a6 = fmaf(x, wr[6], a6); a7 = fmaf(x, wr[7], a7);
      }
      float* yr = Ys + lane * YSTR;
      yr[0]=a0; yr[1]=a1; yr[2]=a2; yr[3]=a3;
      yr[4]=a4; yr[5]=a5; yr[6]=a6; yr[7]=a7;
    }
    __syncthreads();
    {
      const int a_ = lane >> 3, e_ = lane & 7;
      float s = 0.f;
#pragma unroll
      for (int c = 0; c < C_DIM; ++c)
        s = fmaf(w1s[c * 8 + a_], Ys[c * YSTR + e_], s);
      M1s[g * 64 + lane] = s;          // G[a_][e_]
    }
    __syncthreads();
  };

#pragma unroll 1
  for (int g = 0; g < 8; g += 2) {
    loadrow(xrB, g + 1);
    computeA(xrA, g);
    if (g + 2 < 8) loadrow(xrA, g + 2);
    computeA(xrB, g + 1);
  }

  // ---- B phase: 8 lanes per batch (R18 verbatim, M1 = G + G^T on load) ----
  const int e = lane & 7;
  const int g = lane >> 3;
  float a[8], u[8], m2[8];
  float* Wg = &Wbuf[g * WSTRIDE];

#pragma unroll
  for (int j = 0; j < 8; ++j)
    a[j] = M1s[g * 64 + e * 8 + j] + M1s[g * 64 + j * 8 + e];

  // ---- M2 = w2^T M1 w2 directly (rec(M1)=M1) ----
  {
    float t[8];
#pragma unroll
    for (int j = 0; j < 8; ++j) t[j] = 0.f;
#pragma unroll
    for (int k = 0; k < 8; ++k) {
      float4 q0 = *(const float4*)(w2s + k * 8);
      float4 q1 = *(const float4*)(w2s + k * 8 + 4);
      t[0] = fmaf(a[k], q0.x, t[0]); t[1] = fmaf(a[k], q0.y, t[1]);
      t[2] = fmaf(a[k], q0.z, t[2]); t[3] = fmaf(a[k], q0.w, t[3]);
      t[4] = fmaf(a[k], q1.x, t[4]); t[5] = fmaf(a[k], q1.y, t[5]);
      t[6] = fmaf(a[k], q1.z, t[6]); t[7] = fmaf(a[k], q1.w, t[7]);
    }
#pragma unroll
    for (int j = 0; j < 8; ++j) Wg[e * 8 + j] = t[j];
  }
  __syncthreads();
  {
    float tcol[8];
#pragma unroll
    for (int k = 0; k < 8; ++k) tcol[k] = Wg[k * 8 + e];
#pragma unroll
    for (int i = 0; i < 8; ++i) m2[i] = 0.f;
#pragma unroll
    for (int k = 0; k < 8; ++k) {
      float4 q0 = *(const float4*)(w2s + k * 8);
      float4 q1 = *(const float4*)(w2s + k * 8 + 4);
      m2[0] = fmaf(q0.x, tcol[k], m2[0]); m2[1] = fmaf(q0.y, tcol[k], m2[1]);
      m2[2] = fmaf(q0.z, tcol[k], m2[2]); m2[3] = fmaf(q0.w, tcol[k], m2[3]);
      m2[4] = fmaf(q1.x, tcol[k], m2[4]); m2[5] = fmaf(q1.y, tcol[k], m2[5]);
      m2[6] = fmaf(q1.z, tcol[k], m2[6]); m2[7] = fmaf(q1.w, tcol[k], m2[7]);
    }
  }
  __syncthreads();

  // ---- eig + fused rec+logm ----
  xperm8(m2, e);
  jacobi8rel(m2, u, e);
  float lw = logf(fmaxf(m2[0], EPSV));
#pragma unroll
  for (int i = 0; i < 8; ++i) Wg[e * 8 + i] = u[i];
  lwbuf[g * 8 + e] = lw;
  __syncthreads();
  {
    float mk[8];
#pragma unroll
    for (int k = 0; k < 8; ++k) mk[k] = lwbuf[g * 8 + k] * Wg[k * 8 + e];
    float fcol[8];
#pragma unroll
    for (int i = 0; i < 8; ++i) fcol[i] = 0.f;
#pragma unroll
    for (int k = 0; k < 8; ++k) {
      float4 q0 = *(const float4*)&Wg[k * 8 + 0];
      float4 q1 = *(const float4*)&Wg[k * 8 + 4];
      fcol[0] = fmaf(q0.x, mk[k], fcol[0]); fcol[1] = fmaf(q0.y, mk[k], fcol[1]);
      fcol[2] = fmaf(q0.z, mk[k], fcol[2]); fcol[3] = fmaf(q0.w, mk[k], fcol[3]);
      fcol[4] = fmaf(q1.x, mk[k], fcol[4]); fcol[5] = fmaf(q1.y, mk[k], fcol[5]);
      fcol[6] = fmaf(q1.z, mk[k], fcol[6]); fcol[7] = fmaf(q1.w, mk[k], fcol[7]);
    }
    float l0 = 0.f, l1 = 0.f;
    const int b = b0 + g;
    float* featg = out + 2 * (size_t)B_TOTAL + (size_t)b * 64;
#pragma unroll
    for (int i = 0; i < 8; ++i) {
      featg[i * 8 + e] = fcol[i];
      l0 = fmaf(fcol[i], fcs[(i * 8 + e) * 2 + 0], l0);
      l1 = fmaf(fcol[i], fcs[(i * 8 + e) * 2 + 1], l1);
    }
    l0 += sx<1>(l0); l0 += sx<2>(l0); l0 += sx<4>(l0);
    l1 += sx<1>(l1); l1 += sx<2>(l1); l1 += sx<4>(l1);
    float mx = fmaxf(l0, l1);
    float lse = mx + logf(expf(l0 - mx) + expf(l1 - mx));
    if (e < 2) out[(size_t)b * 2 + e] = (e ? l1 : l0) - lse;
  }
}

extern "C" void kernel_launch(void* const* d_in, const int* in_sizes, int n_in,
                              void* d_out, int out_size, void* d_ws, size_t ws_size,
                              hipStream_t stream) {
  const float* X  = (const float*)d_in[0];   // [8192,62,62]
  const float* w1 = (const float*)d_in[1];   // [62,8]
  const float* w2 = (const float*)d_in[2];   // [8,8]
  const float* fc = (const float*)d_in[3];   // [64,2]
  float* out = (float*)d_out;                // [8192*2] ++ [8192*64]

  spdnet_kernel<<<B_TOTAL / 8, 64, 0, stream>>>(X, w1, w2, fc, out);
}

// Round 23
// 39.918 us; speedup vs baseline: 2.1545x; 2.1545x over previous
//
#include <hip/hip_runtime.h>
#include <math.h>

#define B_TOTAL 8192
#define C_DIM 62
#define CC (C_DIM * C_DIM)   // 3844 floats
#define EPSV 1e-4f
#define NSWEEP 4
#define WSTRIDE 72
#define YSTR 9

// NOTE (R15): __syncthreads = vital scheduling fence (keeps VGPR bounded).
// NOTE (R16): eig1 removed — rec(M1)=M1 for this data (absmax guards).
// NOTE (R17): Y-loop w1 reads via wave-uniform global (scalar s_load path).
// NOTE (R22): triangle-read regressed (branchy loads kill ILP; cache lines
// shared) — A uses flat row reads. NOTE (R23): 2-wave block; A split 4+4
// (2 waves/SIMD during the BW-bound phase), B on wave 0 verbatim R18.

// ---------- cross-lane xor-shuffle: DPP (VALU) for masks 1..3, swizzle 4..7 ----------
template<int M> __device__ __forceinline__ float sx(float x) {
  int xi = __builtin_bit_cast(int, x);
  int r;
  if constexpr (M == 1)      r = __builtin_amdgcn_update_dpp(xi, xi, 0xB1, 0xF, 0xF, false);
  else if constexpr (M == 2) r = __builtin_amdgcn_update_dpp(xi, xi, 0x4E, 0xF, 0xF, false);
  else if constexpr (M == 3) r = __builtin_amdgcn_update_dpp(xi, xi, 0x1B, 0xF, 0xF, false);
  else                       r = __builtin_amdgcn_ds_swizzle(xi, (M << 10) | 0x1F);
  return __builtin_bit_cast(float, r);
}

// in-register xor-permute: r[j] <- r[j ^ e]
__device__ __forceinline__ void xperm8(float r[8], const int e) {
  const bool b0 = (e & 1) != 0, b1 = (e & 2) != 0, b2 = (e & 4) != 0;
  float t0[8], t1[8];
#pragma unroll
  for (int j = 0; j < 8; ++j) t0[j] = b0 ? r[j ^ 1] : r[j];
#pragma unroll
  for (int j = 0; j < 8; ++j) t1[j] = b1 ? t0[j ^ 2] : t0[j];
#pragma unroll
  for (int j = 0; j < 8; ++j) r[j] = b2 ? t1[j ^ 4] : t1[j];
}

// ---------- one tournament stage, XOR-relative storage ----------
template<int M>
__device__ __forceinline__ void jstage(float ar[8], float pr[8], const int e) {
  constexpr int HB = (M >= 4) ? 4 : ((M >= 2) ? 2 : 1);
  constexpr int A1 = (M == 1) ? 2 : 1;
  constexpr int A2 = (M <= 3) ? 4 : 2;
  const bool low = (e & HB) == 0;
  float d_oth = sx<M>(ar[0]);
  float o_oth = sx<M>(ar[M]);
  float apq = 0.5f * (ar[M] + o_oth);
  float app = low ? ar[0] : d_oth;
  float aqq = low ? d_oth : ar[0];
  float taun = aqq - app;
  float den = fabsf(taun) + sqrtf(fmaf(taun, taun, 4.f * apq * apq)) + 1e-38f;
  float t = (2.f * apq) * copysignf(1.f, taun) * __builtin_amdgcn_rcpf(den);
  float c = rsqrtf(fmaf(t, t, 1.f));
  float s = t * c;
  float cg[8], sg[8];
  cg[0] = c;  sg[0] = s;
  cg[A1] = sx<A1>(c);  sg[A1] = sx<A1>(s);
  cg[A2] = sx<A2>(c);  sg[A2] = sx<A2>(s);
  cg[A1 ^ A2] = sx<A2>(cg[A1]);  sg[A1 ^ A2] = sx<A2>(sg[A1]);
  float an[8], pn[8];
#pragma unroll
  for (int d = 0; d < 8; ++d) {
    const int rep = (d == 0 || d == A1 || d == A2 || d == (A1 ^ A2)) ? d : (d ^ M);
    const bool flip = (d & HB) != 0;
    float sD = sg[rep];
    float ss = (low != flip) ? -sD : sD;
    an[d] = fmaf(cg[rep], ar[d], ss * ar[d ^ M]);
    pn[d] = fmaf(cg[rep], pr[d], ss * pr[d ^ M]);
  }
#pragma unroll
  for (int d = 0; d < 8; ++d) pr[d] = pn[d];
  float scol = low ? -s : s;
  float aoth[8];
#pragma unroll
  for (int d = 0; d < 8; ++d) aoth[d] = sx<M>(an[d ^ M]);
#pragma unroll
  for (int d = 0; d < 8; ++d) ar[d] = fmaf(c, an[d], scol * aoth[d]);
}

__device__ __forceinline__ void jacobi8rel(float ar[8], float u[8], const int e) {
  float pr[8];
#pragma unroll
  for (int i = 0; i < 8; ++i) pr[i] = (i == 0) ? 1.f : 0.f;
#pragma unroll 1
  for (int sweep = 0; sweep < NSWEEP; ++sweep) {
    jstage<1>(ar, pr, e);
    jstage<2>(ar, pr, e);
    jstage<3>(ar, pr, e);
    jstage<4>(ar, pr, e);
    jstage<5>(ar, pr, e);
    jstage<6>(ar, pr, e);
    jstage<7>(ar, pr, e);
  }
  u[0] = pr[0];
  u[1] = sx<1>(pr[1]);
  u[2] = sx<2>(pr[2]);
  u[3] = sx<3>(pr[3]);
  u[4] = sx<4>(pr[4]);
  u[5] = sx<5>(pr[5]);
  u[6] = sx<6>(pr[6]);
  u[7] = sx<7>(pr[7]);
  xperm8(u, e);
}

// ---------------- fused kernel: 2 waves; A = 4+4 batches, B = wave 0 ----------------
__global__ __launch_bounds__(128) void spdnet_kernel(
    const float* __restrict__ X, const float* __restrict__ w1,
    const float* __restrict__ w2, const float* __restrict__ fc,
    float* __restrict__ out) {
  __shared__ __align__(16) float w1s[C_DIM * 8];
  __shared__ float Ys[2][C_DIM * YSTR];          // one per wave
  __shared__ float M1s[8 * 64];
  __shared__ __align__(16) float Wbuf[8 * WSTRIDE];
  __shared__ float lwbuf[64];
  __shared__ float w2s[64];
  __shared__ float fcs[128];
  const int tid = threadIdx.x;
  const int lane = tid & 63;
  const int wv = tid >> 6;          // 0 or 1
  const int b0 = blockIdx.x * 8;
  const int b0w = b0 + wv * 4;      // this wave's 4 A-batches

  if (tid < 64) w2s[tid] = w2[tid];
  fcs[tid] = fc[tid];
  if (tid < C_DIM) {
    *(float4*)(w1s + tid * 8)     = *(const float4*)(w1 + tid * 8);
    *(float4*)(w1s + tid * 8 + 4) = *(const float4*)(w1 + tid * 8 + 4);
  }

  // ---- A phase: each wave does 4 batches, ping-pong register prefetch ----
  float xrA[C_DIM], xrB[C_DIM];
  if (lane < C_DIM) {
    const float* row = X + (size_t)b0w * CC + lane * C_DIM;
#pragma unroll
    for (int k = 0; k < 31; ++k) {
      float2 t = *(const float2*)(row + 2 * k);
      xrA[2 * k] = t.x; xrA[2 * k + 1] = t.y;
    }
  }
  __syncthreads();

  auto loadrow = [&](float* r, int g) {
    if (lane < C_DIM) {
      const float* row = X + (size_t)(b0w + g) * CC + lane * C_DIM;
#pragma unroll
      for (int k = 0; k < 31; ++k) {
        float2 t = *(const float2*)(row + 2 * k);
        r[2 * k] = t.x; r[2 * k + 1] = t.y;
      }
    }
  };
  auto computeA = [&](const float* xr, int g) {
    if (lane < C_DIM) {
      float a0=0.f,a1=0.f,a2=0.f,a3=0.f,a4=0.f,a5=0.f,a6=0.f,a7=0.f;
#pragma unroll
      for (int d = 0; d < C_DIM; ++d) {
        float x = xr[d];
        const float* wr = w1 + d * 8;   // wave-uniform -> scalar path
        a0 = fmaf(x, wr[0], a0); a1 = fmaf(x, wr[1], a1);
        a2 = fmaf(x, wr[2], a2); a3 = fmaf(x, wr[3], a3);
        a4 = fmaf(x, wr[4], a4); a5 = fmaf(x, wr[5], a5);
        a6 = fmaf(x, wr[6], a6); a7 = fmaf(x, wr[7], a7);
      }
      float* yr = Ys[wv] + lane * YSTR;
      yr[0]=a0; yr[1]=a1; yr[2]=a2; yr[3]=a3;
      yr[4]=a4; yr[5]=a5; yr[6]=a6; yr[7]=a7;
    }
    __syncthreads();
    {
      const int a_ = lane >> 3, e_ = lane & 7;
      float s = 0.f;
#pragma unroll
      for (int c = 0; c < C_DIM; ++c)
        s = fmaf(w1s[c * 8 + a_], Ys[wv][c * YSTR + e_], s);
      M1s[(wv * 4 + g) * 64 + lane] = s;
    }
    __syncthreads();
  };

#pragma unroll 1
  for (int g = 0; g < 4; g += 2) {
    loadrow(xrB, g + 1);                 // prefetch g+1; flies under computeA(g)
    computeA(xrA, g);
    if (g + 2 < 4) loadrow(xrA, g + 2);  // prefetch g+2
    computeA(xrB, g + 1);
  }

  // ---- B phase: wave 0 only, 8 lanes per batch (R18 verbatim) ----
  const int e = tid & 7;
  const int g = (tid >> 3) & 7;
  const bool bact = (tid < 64);
  float a[8], u[8], m2[8];
  float* Wg = &Wbuf[g * WSTRIDE];

  if (bact) {
#pragma unroll
    for (int j = 0; j < 8; ++j) a[j] = M1s[g * 64 + e * 8 + j];
    // ---- M2 = w2^T M1 w2 directly (rec(M1)=M1) ----
    float t[8];
#pragma unroll
    for (int j = 0; j < 8; ++j) t[j] = 0.f;
#pragma unroll
    for (int k = 0; k < 8; ++k) {
      float4 q0 = *(const float4*)(w2s + k * 8);
      float4 q1 = *(const float4*)(w2s + k * 8 + 4);
      t[0] = fmaf(a[k], q0.x, t[0]); t[1] = fmaf(a[k], q0.y, t[1]);
      t[2] = fmaf(a[k], q0.z, t[2]); t[3] = fmaf(a[k], q0.w, t[3]);
      t[4] = fmaf(a[k], q1.x, t[4]); t[5] = fmaf(a[k], q1.y, t[5]);
      t[6] = fmaf(a[k], q1.z, t[6]); t[7] = fmaf(a[k], q1.w, t[7]);
    }
#pragma unroll
    for (int j = 0; j < 8; ++j) Wg[e * 8 + j] = t[j];
  }
  __syncthreads();
  if (bact) {
    float tcol[8];
#pragma unroll
    for (int k = 0; k < 8; ++k) tcol[k] = Wg[k * 8 + e];
#pragma unroll
    for (int i = 0; i < 8; ++i) m2[i] = 0.f;
#pragma unroll
    for (int k = 0; k < 8; ++k) {
      float4 q0 = *(const float4*)(w2s + k * 8);
      float4 q1 = *(const float4*)(w2s + k * 8 + 4);
      m2[0] = fmaf(q0.x, tcol[k], m2[0]); m2[1] = fmaf(q0.y, tcol[k], m2[1]);
      m2[2] = fmaf(q0.z, tcol[k], m2[2]); m2[3] = fmaf(q0.w, tcol[k], m2[3]);
      m2[4] = fmaf(q1.x, tcol[k], m2[4]); m2[5] = fmaf(q1.y, tcol[k], m2[5]);
      m2[6] = fmaf(q1.z, tcol[k], m2[6]); m2[7] = fmaf(q1.w, tcol[k], m2[7]);
    }
  }
  __syncthreads();  // Wbuf reads done before reuse
  if (bact) {
    // ---- eig + fused rec+logm ----
    xperm8(m2, e);
    jacobi8rel(m2, u, e);
    float lw = logf(fmaxf(m2[0], EPSV));
#pragma unroll
    for (int i = 0; i < 8; ++i) Wg[e * 8 + i] = u[i];
    lwbuf[g * 8 + e] = lw;
  }
  __syncthreads();
  if (bact) {
    float mk[8];
#pragma unroll
    for (int k = 0; k < 8; ++k) mk[k] = lwbuf[g * 8 + k] * Wg[k * 8 + e];
    float fcol[8];
#pragma unroll
    for (int i = 0; i < 8; ++i) fcol[i] = 0.f;
#pragma unroll
    for (int k = 0; k < 8; ++k) {
      float4 q0 = *(const float4*)&Wg[k * 8 + 0];
      float4 q1 = *(const float4*)&Wg[k * 8 + 4];
      fcol[0] = fmaf(q0.x, mk[k], fcol[0]); fcol[1] = fmaf(q0.y, mk[k], fcol[1]);
      fcol[2] = fmaf(q0.z, mk[k], fcol[2]); fcol[3] = fmaf(q0.w, mk[k], fcol[3]);
      fcol[4] = fmaf(q1.x, mk[k], fcol[4]); fcol[5] = fmaf(q1.y, mk[k], fcol[5]);
      fcol[6] = fmaf(q1.z, mk[k], fcol[6]); fcol[7] = fmaf(q1.w, mk[k], fcol[7]);
    }
    float l0 = 0.f, l1 = 0.f;
    const int b = b0 + g;
    float* featg = out + 2 * (size_t)B_TOTAL + (size_t)b * 64;
#pragma unroll
    for (int i = 0; i < 8; ++i) {
      featg[i * 8 + e] = fcol[i];
      l0 = fmaf(fcol[i], fcs[(i * 8 + e) * 2 + 0], l0);
      l1 = fmaf(fcol[i], fcs[(i * 8 + e) * 2 + 1], l1);
    }
    l0 += sx<1>(l0); l0 += sx<2>(l0); l0 += sx<4>(l0);
    l1 += sx<1>(l1); l1 += sx<2>(l1); l1 += sx<4>(l1);
    float mx = fmaxf(l0, l1);
    float lse = mx + logf(expf(l0 - mx) + expf(l1 - mx));
    if (e < 2) out[(size_t)b * 2 + e] = (e ? l1 : l0) - lse;
  }
}

extern "C" void kernel_launch(void* const* d_in, const int* in_sizes, int n_in,
                              void* d_out, int out_size, void* d_ws, size_t ws_size,
                              hipStream_t stream) {
  const float* X  = (const float*)d_in[0];   // [8192,62,62]
  const float* w1 = (const float*)d_in[1];   // [62,8]
  const float* w2 = (const float*)d_in[2];   // [8,8]
  const float* fc = (const float*)d_in[3];   // [64,2]
  float* out = (float*)d_out;                // [8192*2] ++ [8192*64]

  spdnet_kernel<<<B_TOTAL / 8, 128, 0, stream>>>(X, w1, w2, fc, out);
}

// Round 24
// 37.608 us; speedup vs baseline: 2.2868x; 1.0614x over previous
//
#include <hip/hip_runtime.h>
#include <math.h>

#define B_TOTAL 8192
#define C_DIM 62
#define CC (C_DIM * C_DIM)   // 3844 floats
#define EPSV 1e-4f
#define NSWEEP 4
#define WSTRIDE 72
#define YSTR 9

// FINAL CONFIG (R18, measured optimum over 23 rounds):
// - fused single kernel, 1 wave = 8 batches (1024 waves = 1/SIMD)
// - A: per-lane X-row register reads (flat, ILP-31), ping-pong prefetch,
//   w1 via wave-uniform global (scalar s_load path), Ys stride-9 exchange
// - rec(M1)=M1 identity (lambda_min >> 1e-4) -> direct M2 = w2^T M1 w2
// - B: one 8-lane XOR-tournament Jacobi (NSWEEP=4), P=U^T row-update trick,
//   fused rec+logm, feat/logits/log_softmax in-wave
// Falsified alternatives: LDS-staged A (R4/R5), triangle reads (R22),
// 2-wave splits (R14/R21/R23), all-DPP comm (R10), barrier removal (R15).

// ---------- cross-lane xor-shuffle: DPP (VALU) for masks 1..3, swizzle 4..7 ----------
template<int M> __device__ __forceinline__ float sx(float x) {
  int xi = __builtin_bit_cast(int, x);
  int r;
  if constexpr (M == 1)      r = __builtin_amdgcn_update_dpp(xi, xi, 0xB1, 0xF, 0xF, false);
  else if constexpr (M == 2) r = __builtin_amdgcn_update_dpp(xi, xi, 0x4E, 0xF, 0xF, false);
  else if constexpr (M == 3) r = __builtin_amdgcn_update_dpp(xi, xi, 0x1B, 0xF, 0xF, false);
  else                       r = __builtin_amdgcn_ds_swizzle(xi, (M << 10) | 0x1F);
  return __builtin_bit_cast(float, r);
}

// in-register xor-permute: r[j] <- r[j ^ e]
__device__ __forceinline__ void xperm8(float r[8], const int e) {
  const bool b0 = (e & 1) != 0, b1 = (e & 2) != 0, b2 = (e & 4) != 0;
  float t0[8], t1[8];
#pragma unroll
  for (int j = 0; j < 8; ++j) t0[j] = b0 ? r[j ^ 1] : r[j];
#pragma unroll
  for (int j = 0; j < 8; ++j) t1[j] = b1 ? t0[j ^ 2] : t0[j];
#pragma unroll
  for (int j = 0; j < 8; ++j) r[j] = b2 ? t1[j ^ 4] : t1[j];
}

// ---------- one tournament stage, XOR-relative storage ----------
// lane e stores ar[d] = A[e^d][e], pr[d] = P[e^d][e] with P = U^T (row-update
// only -> zero shuffles for the accumulator).
template<int M>
__device__ __forceinline__ void jstage(float ar[8], float pr[8], const int e) {
  constexpr int HB = (M >= 4) ? 4 : ((M >= 2) ? 2 : 1);
  constexpr int A1 = (M == 1) ? 2 : 1;
  constexpr int A2 = (M <= 3) ? 4 : 2;
  const bool low = (e & HB) == 0;
  float d_oth = sx<M>(ar[0]);
  float o_oth = sx<M>(ar[M]);
  float apq = 0.5f * (ar[M] + o_oth);
  float app = low ? ar[0] : d_oth;
  float aqq = low ? d_oth : ar[0];
  float taun = aqq - app;
  float den = fabsf(taun) + sqrtf(fmaf(taun, taun, 4.f * apq * apq)) + 1e-38f;
  float t = (2.f * apq) * copysignf(1.f, taun) * __builtin_amdgcn_rcpf(den);
  float c = rsqrtf(fmaf(t, t, 1.f));
  float s = t * c;
  float cg[8], sg[8];
  cg[0] = c;  sg[0] = s;
  cg[A1] = sx<A1>(c);  sg[A1] = sx<A1>(s);
  cg[A2] = sx<A2>(c);  sg[A2] = sx<A2>(s);
  cg[A1 ^ A2] = sx<A2>(cg[A1]);  sg[A1 ^ A2] = sx<A2>(sg[A1]);
  float an[8], pn[8];
#pragma unroll
  for (int d = 0; d < 8; ++d) {
    const int rep = (d == 0 || d == A1 || d == A2 || d == (A1 ^ A2)) ? d : (d ^ M);
    const bool flip = (d & HB) != 0;
    float sD = sg[rep];
    float ss = (low != flip) ? -sD : sD;
    an[d] = fmaf(cg[rep], ar[d], ss * ar[d ^ M]);
    pn[d] = fmaf(cg[rep], pr[d], ss * pr[d ^ M]);
  }
#pragma unroll
  for (int d = 0; d < 8; ++d) pr[d] = pn[d];
  float scol = low ? -s : s;
  float aoth[8];
#pragma unroll
  for (int d = 0; d < 8; ++d) aoth[d] = sx<M>(an[d ^ M]);
#pragma unroll
  for (int d = 0; d < 8; ++d) ar[d] = fmaf(c, an[d], scol * aoth[d]);
}

__device__ __forceinline__ void jacobi8rel(float ar[8], float u[8], const int e) {
  float pr[8];
#pragma unroll
  for (int i = 0; i < 8; ++i) pr[i] = (i == 0) ? 1.f : 0.f;
#pragma unroll 1
  for (int sweep = 0; sweep < NSWEEP; ++sweep) {
    jstage<1>(ar, pr, e);
    jstage<2>(ar, pr, e);
    jstage<3>(ar, pr, e);
    jstage<4>(ar, pr, e);
    jstage<5>(ar, pr, e);
    jstage<6>(ar, pr, e);
    jstage<7>(ar, pr, e);
  }
  u[0] = pr[0];
  u[1] = sx<1>(pr[1]);
  u[2] = sx<2>(pr[2]);
  u[3] = sx<3>(pr[3]);
  u[4] = sx<4>(pr[4]);
  u[5] = sx<5>(pr[5]);
  u[6] = sx<6>(pr[6]);
  u[7] = sx<7>(pr[7]);
  xperm8(u, e);   // u[i] = U[i][e]
}

// ---------------- fused kernel: 1 wave = 8 batches, A phase then B phase ----------------
__global__ __launch_bounds__(64) void spdnet_kernel(
    const float* __restrict__ X, const float* __restrict__ w1,
    const float* __restrict__ w2, const float* __restrict__ fc,
    float* __restrict__ out) {
  __shared__ __align__(16) float w1s[C_DIM * 8];
  __shared__ float Ys[C_DIM * YSTR];
  __shared__ float M1s[8 * 64];
  __shared__ __align__(16) float Wbuf[8 * WSTRIDE];
  __shared__ float lwbuf[64];
  __shared__ float w2s[64];
  __shared__ float fcs[128];
  const int lane = threadIdx.x;
  const int b0 = blockIdx.x * 8;

  w2s[lane] = w2[lane];
  fcs[lane] = fc[lane];
  fcs[lane + 64] = fc[lane + 64];
  if (lane < C_DIM) {
    *(float4*)(w1s + lane * 8)     = *(const float4*)(w1 + lane * 8);
    *(float4*)(w1s + lane * 8 + 4) = *(const float4*)(w1 + lane * 8 + 4);
  }

  // ---- A phase: M1[g] = w1^T X[b0+g] w1, ping-pong register prefetch ----
  float xrA[C_DIM], xrB[C_DIM];
  if (lane < C_DIM) {
    const float* row = X + (size_t)b0 * CC + lane * C_DIM;
#pragma unroll
    for (int k = 0; k < 31; ++k) {
      float2 t = *(const float2*)(row + 2 * k);
      xrA[2 * k] = t.x; xrA[2 * k + 1] = t.y;
    }
  }
  __syncthreads();

  auto loadrow = [&](float* r, int g) {
    if (lane < C_DIM) {
      const float* row = X + (size_t)(b0 + g) * CC + lane * C_DIM;
#pragma unroll
      for (int k = 0; k < 31; ++k) {
        float2 t = *(const float2*)(row + 2 * k);
        r[2 * k] = t.x; r[2 * k + 1] = t.y;
      }
    }
  };
  auto computeA = [&](const float* xr, int g) {
    if (lane < C_DIM) {
      float a0=0.f,a1=0.f,a2=0.f,a3=0.f,a4=0.f,a5=0.f,a6=0.f,a7=0.f;
#pragma unroll
      for (int d = 0; d < C_DIM; ++d) {
        float x = xr[d];
        const float* wr = w1 + d * 8;   // wave-uniform -> scalar path
        a0 = fmaf(x, wr[0], a0); a1 = fmaf(x, wr[1], a1);
        a2 = fmaf(x, wr[2], a2); a3 = fmaf(x, wr[3], a3);
        a4 = fmaf(x, wr[4], a4); a5 = fmaf(x, wr[5], a5);
        a6 = fmaf(x, wr[6], a6); a7 = fmaf(x, wr[7], a7);
      }
      float* yr = Ys + lane * YSTR;
      yr[0]=a0; yr[1]=a1; yr[2]=a2; yr[3]=a3;
      yr[4]=a4; yr[5]=a5; yr[6]=a6; yr[7]=a7;
    }
    __syncthreads();
    {
      const int a_ = lane >> 3, e_ = lane & 7;
      float s = 0.f;
#pragma unroll
      for (int c = 0; c < C_DIM; ++c)
        s = fmaf(w1s[c * 8 + a_], Ys[c * YSTR + e_], s);
      M1s[g * 64 + lane] = s;
    }
    __syncthreads();
  };

#pragma unroll 1
  for (int g = 0; g < 8; g += 2) {
    loadrow(xrB, g + 1);                 // prefetch g+1; flies under computeA(g)
    computeA(xrA, g);
    if (g + 2 < 8) loadrow(xrA, g + 2);  // prefetch g+2
    computeA(xrB, g + 1);
  }

  // ---- B phase: 8 lanes per batch ----
  const int e = lane & 7;
  const int g = lane >> 3;
  float a[8], u[8], m2[8];
  float* Wg = &Wbuf[g * WSTRIDE];

#pragma unroll
  for (int j = 0; j < 8; ++j) a[j] = M1s[g * 64 + e * 8 + j];

  // ---- M2 = w2^T M1 w2 directly (rec(M1)=M1) ----
  {
    float t[8];
#pragma unroll
    for (int j = 0; j < 8; ++j) t[j] = 0.f;
#pragma unroll
    for (int k = 0; k < 8; ++k) {
      float4 q0 = *(const float4*)(w2s + k * 8);
      float4 q1 = *(const float4*)(w2s + k * 8 + 4);
      t[0] = fmaf(a[k], q0.x, t[0]); t[1] = fmaf(a[k], q0.y, t[1]);
      t[2] = fmaf(a[k], q0.z, t[2]); t[3] = fmaf(a[k], q0.w, t[3]);
      t[4] = fmaf(a[k], q1.x, t[4]); t[5] = fmaf(a[k], q1.y, t[5]);
      t[6] = fmaf(a[k], q1.z, t[6]); t[7] = fmaf(a[k], q1.w, t[7]);
    }
#pragma unroll
    for (int j = 0; j < 8; ++j) Wg[e * 8 + j] = t[j];
  }
  __syncthreads();
  {
    float tcol[8];
#pragma unroll
    for (int k = 0; k < 8; ++k) tcol[k] = Wg[k * 8 + e];
#pragma unroll
    for (int i = 0; i < 8; ++i) m2[i] = 0.f;
#pragma unroll
    for (int k = 0; k < 8; ++k) {
      float4 q0 = *(const float4*)(w2s + k * 8);
      float4 q1 = *(const float4*)(w2s + k * 8 + 4);
      m2[0] = fmaf(q0.x, tcol[k], m2[0]); m2[1] = fmaf(q0.y, tcol[k], m2[1]);
      m2[2] = fmaf(q0.z, tcol[k], m2[2]); m2[3] = fmaf(q0.w, tcol[k], m2[3]);
      m2[4] = fmaf(q1.x, tcol[k], m2[4]); m2[5] = fmaf(q1.y, tcol[k], m2[5]);
      m2[6] = fmaf(q1.z, tcol[k], m2[6]); m2[7] = fmaf(q1.w, tcol[k], m2[7]);
    }
  }
  __syncthreads();

  // ---- eig + fused rec+logm ----
  xperm8(m2, e);
  jacobi8rel(m2, u, e);
  float lw = logf(fmaxf(m2[0], EPSV));
#pragma unroll
  for (int i = 0; i < 8; ++i) Wg[e * 8 + i] = u[i];
  lwbuf[g * 8 + e] = lw;
  __syncthreads();
  {
    float mk[8];
#pragma unroll
    for (int k = 0; k < 8; ++k) mk[k] = lwbuf[g * 8 + k] * Wg[k * 8 + e];
    float fcol[8];
#pragma unroll
    for (int i = 0; i < 8; ++i) fcol[i] = 0.f;
#pragma unroll
    for (int k = 0; k < 8; ++k) {
      float4 q0 = *(const float4*)&Wg[k * 8 + 0];
      float4 q1 = *(const float4*)&Wg[k * 8 + 4];
      fcol[0] = fmaf(q0.x, mk[k], fcol[0]); fcol[1] = fmaf(q0.y, mk[k], fcol[1]);
      fcol[2] = fmaf(q0.z, mk[k], fcol[2]); fcol[3] = fmaf(q0.w, mk[k], fcol[3]);
      fcol[4] = fmaf(q1.x, mk[k], fcol[4]); fcol[5] = fmaf(q1.y, mk[k], fcol[5]);
      fcol[6] = fmaf(q1.z, mk[k], fcol[6]); fcol[7] = fmaf(q1.w, mk[k], fcol[7]);
    }
    float l0 = 0.f, l1 = 0.f;
    const int b = b0 + g;
    float* featg = out + 2 * (size_t)B_TOTAL + (size_t)b * 64;
#pragma unroll
    for (int i = 0; i < 8; ++i) {
      featg[i * 8 + e] = fcol[i];
      l0 = fmaf(fcol[i], fcs[(i * 8 + e) * 2 + 0], l0);
      l1 = fmaf(fcol[i], fcs[(i * 8 + e) * 2 + 1], l1);
    }
    l0 += sx<1>(l0); l0 += sx<2>(l0); l0 += sx<4>(l0);
    l1 += sx<1>(l1); l1 += sx<2>(l1); l1 += sx<4>(l1);
    float mx = fmaxf(l0, l1);
    float lse = mx + logf(expf(l0 - mx) + expf(l1 - mx));
    if (e < 2) out[(size_t)b * 2 + e] = (e ? l1 : l0) - lse;
  }
}

extern "C" void kernel_launch(void* const* d_in, const int* in_sizes, int n_in,
                              void* d_out, int out_size, void* d_ws, size_t ws_size,
                              hipStream_t stream) {
  const float* X  = (const float*)d_in[0];   // [8192,62,62]
  const float* w1 = (const float*)d_in[1];   // [62,8]
  const float* w2 = (const float*)d_in[2];   // [8,8]
  const float* fc = (const float*)d_in[3];   // [64,2]
  float* out = (float*)d_out;                // [8192*2] ++ [8192*64]

  spdnet_kernel<<<B_TOTAL / 8, 64, 0, stream>>>(X, w1, w2, fc, out);
}